// Round 3
// baseline (564.634 us; speedup 1.0000x reference)
//
#include <hip/hip_runtime.h>
#include <hip/hip_cooperative_groups.h>
#include <math.h>

namespace cg = cooperative_groups;

#define BB 8
#define CC 1024
#define LL 4096
#define NPB (CC*LL)          // 4194304 elements per batch
#define TOTAL (BB*CC*LL)     // 33554432

// ws layout:
//   [0,128)    double sums[16]      (S1,S2 per batch)
//   [128,136)  double lossAcc
//   [256, 256+131072)         float ssA[B*L]
//   [256+131072, 256+262144)  float syA[B*L]

// grid (16, 8, 4) x 256 threads = 512 blocks (2 per CU, co-resident).
// lane owns l-quad l0..l0+3; thread covers c in [c0, c0+64).
__global__ __launch_bounds__(256, 2)
void k_fused(const float* __restrict__ xs, const float* __restrict__ xt,
             double* __restrict__ sums, double* __restrict__ lossAcc,
             float* __restrict__ ssA, float* __restrict__ syA,
             float* __restrict__ out) {
    cg::grid_group grid = cg::this_grid();
    const int tid = threadIdx.x;
    const int lane = tid & 63, w = tid >> 6;
    const int bx = blockIdx.x, b = blockIdx.y, bz = blockIdx.z;

    __shared__ float red[4][64][8];
    __shared__ double ls[8];
    __shared__ float shMargin;

    // ---------- Phase A: batch sums of xt (linear slab per batch) ----------
    {
        const float4* p = (const float4*)(xt + (size_t)b * NPB);
        int t = (bx * 4 + bz) * 256 + tid;       // [0, 16384)
        double s1 = 0.0, s2 = 0.0;
        #pragma unroll 4
        for (int i = 0; i < 64; ++i) {
            float4 v = p[t + (size_t)i * 16384];
            float q1 = (v.x + v.y) + (v.z + v.w);
            float q2 = (v.x * v.x + v.y * v.y) + (v.z * v.z + v.w * v.w);
            s1 += (double)q1;
            s2 += (double)q2;
        }
        for (int off = 32; off; off >>= 1) {
            s1 += __shfl_down(s1, off, 64);
            s2 += __shfl_down(s2, off, 64);
        }
        if (lane == 0) { ls[w] = s1; ls[4 + w] = s2; }
        __syncthreads();
        if (tid == 0) {
            atomicAdd(&sums[2 * b],     ls[0] + ls[1] + ls[2] + ls[3]);
            atomicAdd(&sums[2 * b + 1], ls[4] + ls[5] + ls[6] + ls[7]);
        }
    }
    grid.sync();

    // ---------- Phase B: margin (redundant per block, exact ref formula) ----------
    if (tid == 0) {
        double n = (double)NPB;
        double s1 = sums[2 * b], s2 = sums[2 * b + 1];
        double mean = s1 / n;
        double var = (s2 - s1 * s1 / n) / (n - 1.0);   // ddof=1
        double sd = sqrt(var);
        double z = -mean / sd;
        double cdf = 0.5 * (1.0 + erf(z / 1.4142135623730951));
        double safe = fmax(cdf, 1e-30);
        double r = mean / sd;
        double ma = -sd * exp(-r * r * 0.5) / 2.5066282746310002 / safe + mean;
        shMargin = (float)((cdf > 0.001) ? ma : -3.0 * sd);
    }
    __syncthreads();
    const float mg = shMargin;

    // ---------- Phase C: column stats ss = sum exp(xs), sy = sum exp(max(xt,mg)) ----------
    const int l0 = bx * 256 + lane * 4;
    const int c0 = (bz * 4 + w) * 64;
    const float* ps = xs + (size_t)b * NPB + l0;
    const float* pt = xt + (size_t)b * NPB + l0;
    {
        float ss[4] = {0, 0, 0, 0}, sy[4] = {0, 0, 0, 0};
        #pragma unroll 2
        for (int j = 0; j < 16; ++j) {
            float4 vs[4], vt[4];
            #pragma unroll
            for (int k = 0; k < 4; ++k) {
                int c = c0 + j * 4 + k;
                vs[k] = *(const float4*)(ps + (size_t)c * LL);
                vt[k] = *(const float4*)(pt + (size_t)c * LL);
            }
            #pragma unroll
            for (int k = 0; k < 4; ++k) {
                ss[0] += __expf(vs[k].x); ss[1] += __expf(vs[k].y);
                ss[2] += __expf(vs[k].z); ss[3] += __expf(vs[k].w);
                sy[0] += __expf(fmaxf(vt[k].x, mg)); sy[1] += __expf(fmaxf(vt[k].y, mg));
                sy[2] += __expf(fmaxf(vt[k].z, mg)); sy[3] += __expf(fmaxf(vt[k].w, mg));
            }
        }
        __syncthreads();
        #pragma unroll
        for (int k = 0; k < 4; ++k) { red[w][lane][k] = ss[k]; red[w][lane][4 + k] = sy[k]; }
        __syncthreads();
        if (w == 0) {
            #pragma unroll
            for (int k = 0; k < 4; ++k) {
                float vss = red[0][lane][k] + red[1][lane][k] + red[2][lane][k] + red[3][lane][k];
                float vsy = red[0][lane][4+k] + red[1][lane][4+k] + red[2][lane][4+k] + red[3][lane][4+k];
                atomicAdd(&ssA[b * LL + l0 + k], vss);
                atomicAdd(&syA[b * LL + l0 + k], vsy);
            }
        }
    }
    grid.sync();

    // ---------- Phase D: entropy + loss ----------
    {
        float4 ssv = *(const float4*)(ssA + b * LL + l0);   // fresh: atomics lived at LLC
        float4 syv = *(const float4*)(syA + b * LL + l0);
        float A0 = __logf(ssv.x), A1 = __logf(ssv.y), A2 = __logf(ssv.z), A3 = __logf(ssv.w);
        float B0 = __logf(syv.x), B1 = __logf(syv.y), B2 = __logf(syv.z), B3 = __logf(syv.w);
        float* po = out + 1 + (size_t)b * NPB + l0;
        float acc = 0.f;
        #pragma unroll 2
        for (int j = 0; j < 16; ++j) {
            float4 vs[4], vt[4];
            #pragma unroll
            for (int k = 0; k < 4; ++k) {
                int c = c0 + j * 4 + k;
                vs[k] = *(const float4*)(ps + (size_t)c * LL);
                vt[k] = *(const float4*)(pt + (size_t)c * LL);
            }
            #pragma unroll
            for (int k = 0; k < 4; ++k) {
                int c = c0 + j * 4 + k;
                float4 e;
                e.x = __expf(vs[k].x - A0) * (fmaxf(vt[k].x, mg) - B0);
                e.y = __expf(vs[k].y - A1) * (fmaxf(vt[k].y, mg) - B1);
                e.z = __expf(vs[k].z - A2) * (fmaxf(vt[k].z, mg) - B2);
                e.w = __expf(vs[k].w - A3) * (fmaxf(vt[k].w, mg) - B3);
                *(float4*)(po + (size_t)c * LL) = e;
                acc += (e.x + e.y) + (e.z + e.w);
            }
        }
        for (int off = 32; off; off >>= 1) acc += __shfl_down(acc, off, 64);
        __syncthreads();          // red reuse safety
        if (lane == 0) red[0][0][w + 4] = acc;   // park 4 floats
        __syncthreads();
        if (tid == 0) {
            double t = (double)red[0][0][4] + red[0][0][5] + red[0][0][6] + red[0][0][7];
            atomicAdd(lossAcc, t);
        }
    }
    grid.sync();

    // ---------- Phase E: loss finalize ----------
    if (bx == 0 && b == 0 && bz == 0 && tid == 0) {
        out[0] = (float)(-lossAcc[0] / (double)(BB * LL));
    }
}

extern "C" void kernel_launch(void* const* d_in, const int* in_sizes, int n_in,
                              void* d_out, int out_size, void* d_ws, size_t ws_size,
                              hipStream_t stream) {
    const float* x_ts = (const float*)d_in[2];  // source xs
    const float* x_st = (const float*)d_in[3];  // target xt
    float* out = (float*)d_out;

    double* sums    = (double*)d_ws;
    double* lossAcc = (double*)((char*)d_ws + 128);
    float*  ssA     = (float*)((char*)d_ws + 256);
    float*  syA     = (float*)((char*)d_ws + 256 + 131072);

    hipMemsetAsync(d_ws, 0, 256 + 262144, stream);

    void* args[] = { (void*)&x_ts, (void*)&x_st, (void*)&sums, (void*)&lossAcc,
                     (void*)&ssA, (void*)&syA, (void*)&out };
    hipLaunchCooperativeKernel((void*)k_fused, dim3(16, BB, 4), dim3(256),
                               args, 0, stream);
}